// Round 4
// baseline (174.952 us; speedup 1.0000x reference)
//
#include <hip/hip_runtime.h>
#include <hip/hip_bf16.h>

// Sizes for this problem instance
#define BB   2
#define SS   2048
#define HH   16
#define DM_  1024
#define DH_  64
#define NROW 4096   // BB*SS
#define NQKV 3072   // 3 * HH * DH

typedef unsigned short u16;
using short8 = __attribute__((ext_vector_type(8))) short;
using bf16x8 = __attribute__((ext_vector_type(8))) __bf16;
using f32x4  = __attribute__((ext_vector_type(4))) float;

__device__ __forceinline__ u16 f2bf(float f) {
    union { float f; unsigned u; } v; v.f = f;
    unsigned r = v.u + 0x7fffu + ((v.u >> 16) & 1u);
    return (u16)(r >> 16);
}

__device__ __forceinline__ f32x4 mfma16(bf16x8 a, bf16x8 b, f32x4 c) {
    return __builtin_amdgcn_mfma_f32_16x16x32_bf16(a, b, c, 0, 0, 0);
}

// lane l, elem j -> (row = rowOff + (l&15), k = kOff + (l>>4)*8 + j)
__device__ __forceinline__ bf16x8 fragLd(const u16* base, int rowOff, int kOff, int ld) {
    const int l = threadIdx.x & 63;
    return *(const bf16x8*)(base + (rowOff + (l & 15)) * ld + kOff + ((l >> 4) << 3));
}

// async global->LDS, 16B per lane (dest = wave-uniform base + lane*16)
__device__ __forceinline__ void gload16(const void* g, void* l) {
    __builtin_amdgcn_global_load_lds(
        (const __attribute__((address_space(1))) void*)g,
        (__attribute__((address_space(3))) void*)l, 16, 0, 0);
}

// ---------------------------------------------------------------------------
// pack_x: coalesced fp32->bf16 of X + bias pack
// ---------------------------------------------------------------------------
__global__ void pack_x(const float* __restrict__ x, const float* __restrict__ bq,
                       const float* __restrict__ bk, const float* __restrict__ bv,
                       u16* __restrict__ Xb, float* __restrict__ biasQKV) {
    const int tid = blockIdx.x * 256 + threadIdx.x;
    const int nth = gridDim.x * 256;
    for (int i = tid; i < NROW * DM_; i += nth) Xb[i] = f2bf(x[i]);
    for (int i = tid; i < NQKV; i += nth) {
        int mat = i >> 10, h = (i >> 6) & 15, d = i & 63;
        const float* bb = (mat == 0) ? bq : ((mat == 1) ? bk : bv);
        biasQKV[i] = bb[h * DH_ + d];
    }
}

// ---------------------------------------------------------------------------
// trans_w: Wt[(mat*1024+h*64+d)][m] = W[h][m][d], LDS-tiled (coalesced both sides)
// grid (16 m-tiles, 48 mat*h), 256 threads
// ---------------------------------------------------------------------------
__global__ __launch_bounds__(256)
void trans_w(const float* __restrict__ wq, const float* __restrict__ wk,
             const float* __restrict__ wv, u16* __restrict__ Wt) {
    __shared__ float tile[64][65];
    const int hm = blockIdx.y, mat = hm >> 4, h = hm & 15;
    const float* w = (mat == 0) ? wq : ((mat == 1) ? wk : wv);
    const int m0 = blockIdx.x * 64, t = threadIdx.x;
    #pragma unroll
    for (int it = 0; it < 4; ++it) {
        int row = it * 16 + (t >> 4), c4 = (t & 15) * 4;
        float4 v = *(const float4*)&w[((size_t)h * 1024 + m0 + row) * 64 + c4];
        tile[row][c4] = v.x; tile[row][c4 + 1] = v.y;
        tile[row][c4 + 2] = v.z; tile[row][c4 + 3] = v.w;
    }
    __syncthreads();
    #pragma unroll
    for (int it = 0; it < 2; ++it) {
        int c = it * 256 + t, d = c >> 3, mc = (c & 7) * 8;
        u16 buf[8];
        #pragma unroll
        for (int j = 0; j < 8; ++j) buf[j] = f2bf(tile[mc + j][d]);
        *(short8*)&Wt[((size_t)(mat * 1024 + h * 64 + d)) * 1024 + m0 + mc] = *(short8*)buf;
    }
}

// ---------------------------------------------------------------------------
// trans_wo: WoT[n][k] = wo[k][n], LDS-tiled. grid (16 n-tiles, 16 k-tiles)
// ---------------------------------------------------------------------------
__global__ __launch_bounds__(256)
void trans_wo(const float* __restrict__ wo, u16* __restrict__ WoT) {
    __shared__ float tile[64][65];
    const int n0 = blockIdx.x * 64, k0 = blockIdx.y * 64, t = threadIdx.x;
    #pragma unroll
    for (int it = 0; it < 4; ++it) {
        int row = it * 16 + (t >> 4), c4 = (t & 15) * 4;
        float4 v = *(const float4*)&wo[(size_t)(k0 + row) * DM_ + n0 + c4];
        tile[row][c4] = v.x; tile[row][c4 + 1] = v.y;
        tile[row][c4 + 2] = v.z; tile[row][c4 + 3] = v.w;
    }
    __syncthreads();
    #pragma unroll
    for (int it = 0; it < 2; ++it) {
        int c = it * 256 + t, n = c >> 3, kc = (c & 7) * 8;
        u16 buf[8];
        #pragma unroll
        for (int j = 0; j < 8; ++j) buf[j] = f2bf(tile[kc + j][n]);
        *(short8*)&WoT[(size_t)(n0 + n) * DM_ + k0 + kc] = *(short8*)buf;
    }
}

// ---------------------------------------------------------------------------
// gemm_qk: [4096,1024] @ [1024,2048] -> Q (scaled), K   (m97 structure)
// ---------------------------------------------------------------------------
__global__ __launch_bounds__(256)
void gemm_qk(const u16* __restrict__ Xb, const u16* __restrict__ Wt,
             const float* __restrict__ bias, u16* __restrict__ Qs,
             u16* __restrict__ Ks) {
    __shared__ __align__(16) u16 tA[128 * 64];
    __shared__ __align__(16) u16 tB[128 * 64];
    const int brow = blockIdx.x * 128, bcol = blockIdx.y * 128;
    const int t = threadIdx.x, wid = t >> 6, l = t & 63;
    const int wr = (wid >> 1) * 64, wc = (wid & 1) * 64;
    f32x4 acc[4][4] = {};
    for (int k0 = 0; k0 < DM_; k0 += 64) {
        __syncthreads();
        #pragma unroll
        for (int i = 0; i < 4; ++i) {
            const int off = i * 4096 + t * 16;
            const int row = off >> 7, colB = off & 127;
            gload16((const char*)Xb + ((size_t)(brow + row) * DM_ + k0) * 2 + colB,
                    (char*)tA + off);
            gload16((const char*)Wt + ((size_t)(bcol + row) * DM_ + k0) * 2 + colB,
                    (char*)tB + off);
        }
        __syncthreads();
        #pragma unroll
        for (int kc = 0; kc < 64; kc += 32) {
            bf16x8 a[4], b[4];
            #pragma unroll
            for (int i = 0; i < 4; ++i) a[i] = fragLd(tA, wr + i * 16, kc, 64);
            #pragma unroll
            for (int j = 0; j < 4; ++j) b[j] = fragLd(tB, wc + j * 16, kc, 64);
            #pragma unroll
            for (int i = 0; i < 4; ++i)
                #pragma unroll
                for (int j = 0; j < 4; ++j)
                    acc[i][j] = mfma16(a[i], b[j], acc[i][j]);
        }
    }
    #pragma unroll
    for (int i = 0; i < 4; ++i)
        #pragma unroll
        for (int j = 0; j < 4; ++j)
            #pragma unroll
            for (int r = 0; r < 4; ++r) {
                int row = brow + wr + i * 16 + ((l >> 4) << 2) + r;
                int col = bcol + wc + j * 16 + (l & 15);
                float v = acc[i][j][r] + bias[col];
                int h = (col >> 6) & 15, d = col & 63;
                int b = row >> 11, s = row & 2047;
                size_t adr = (((size_t)(b * HH + h)) * SS + s) * DH_ + d;
                if (col < 1024) Qs[adr] = f2bf(v * 0.125f);
                else            Ks[adr] = f2bf(v);
            }
}

// ---------------------------------------------------------------------------
// gemm_v: Vt = WtV @ Xb^T ([1024,1024] @ [1024,4096]) -> Vt[b*1024+n][s]
// coalesced d-major output (no scatter)
// ---------------------------------------------------------------------------
__global__ __launch_bounds__(256)
void gemm_v(const u16* __restrict__ WtV, const u16* __restrict__ Xb,
            const float* __restrict__ biasV, u16* __restrict__ Vt) {
    __shared__ __align__(16) u16 tA[128 * 64];
    __shared__ __align__(16) u16 tB[128 * 64];
    const int brow = blockIdx.x * 128, bcol = blockIdx.y * 128;
    const int t = threadIdx.x, wid = t >> 6, l = t & 63;
    const int wr = (wid >> 1) * 64, wc = (wid & 1) * 64;
    f32x4 acc[4][4] = {};
    for (int k0 = 0; k0 < DM_; k0 += 64) {
        __syncthreads();
        #pragma unroll
        for (int i = 0; i < 4; ++i) {
            const int off = i * 4096 + t * 16;
            const int row = off >> 7, colB = off & 127;
            gload16((const char*)WtV + ((size_t)(brow + row) * DM_ + k0) * 2 + colB,
                    (char*)tA + off);
            gload16((const char*)Xb + ((size_t)(bcol + row) * DM_ + k0) * 2 + colB,
                    (char*)tB + off);
        }
        __syncthreads();
        #pragma unroll
        for (int kc = 0; kc < 64; kc += 32) {
            bf16x8 a[4], b[4];
            #pragma unroll
            for (int i = 0; i < 4; ++i) a[i] = fragLd(tA, wr + i * 16, kc, 64);
            #pragma unroll
            for (int j = 0; j < 4; ++j) b[j] = fragLd(tB, wc + j * 16, kc, 64);
            #pragma unroll
            for (int i = 0; i < 4; ++i)
                #pragma unroll
                for (int j = 0; j < 4; ++j)
                    acc[i][j] = mfma16(a[i], b[j], acc[i][j]);
        }
    }
    #pragma unroll
    for (int i = 0; i < 4; ++i)
        #pragma unroll
        for (int j = 0; j < 4; ++j)
            #pragma unroll
            for (int r = 0; r < 4; ++r) {
                int row = brow + wr + i * 16 + ((l >> 4) << 2) + r;   // n' = h*64+d
                int col = bcol + wc + j * 16 + (l & 15);              // s_glob
                float v = acc[i][j][r] + biasV[row];
                int b = col >> 11, s = col & 2047;
                Vt[((size_t)(b * 1024 + row)) * SS + s] = f2bf(v);
            }
}

// ---------------------------------------------------------------------------
// attn: flash attention, KVBLK=128, fragment-linear LDS, reg-prefetch,
// defer-max, setprio. One (bh, qt) per block; grid ordered largest-qt-first.
// ---------------------------------------------------------------------------
__global__ __launch_bounds__(512)
void attn_fwd(const u16* __restrict__ Qs, const u16* __restrict__ Ks,
              const u16* __restrict__ Vt, u16* __restrict__ Zb) {
    __shared__ __align__(16) u16 fK[8192];    // 128 kseq x 64 d   (16 KiB)
    __shared__ __align__(16) u16 fV[8192];    // 64 d x 128 kseq   (16 KiB)
    __shared__ __align__(16) u16 fP[16384];   // per-wave 16 q x 128 kseq (32 KiB)
    const int bh = blockIdx.y, b = bh >> 4, h = bh & 15;
    const int t = threadIdx.x, wid = t >> 6, l = t & 63;
    const u16* Qp = Qs + (size_t)bh * SS * DH_;
    const u16* Kp = Ks + (size_t)bh * SS * DH_;
    const u16* Vp = Vt + (size_t)bh * DH_ * SS;

    const int c0 = t, c1 = t + 512;
    const int kOff0 = (((c0 >> 7) << 4) + (c0 & 15)) * DH_ + ((c0 >> 6) & 1) * 32 + ((c0 >> 4) & 3) * 8;
    const int kOff1 = (((c1 >> 7) << 4) + (c1 & 15)) * DH_ + ((c1 >> 6) & 1) * 32 + ((c1 >> 4) & 3) * 8;
    const size_t vOff0 = (size_t)(((c0 >> 8) << 4) + (c0 & 15)) * SS + ((c0 >> 6) & 3) * 32 + ((c0 >> 4) & 3) * 8;
    const size_t vOff1 = (size_t)(((c1 >> 8) << 4) + (c1 & 15)) * SS + ((c1 >> 6) & 3) * 32 + ((c1 >> 4) & 3) * 8;
    u16* ldsK0 = fK + c0 * 8;  u16* ldsK1 = fK + c1 * 8;
    u16* ldsV0 = fV + c0 * 8;  u16* ldsV1 = fV + c1 * 8;
    u16* fPw = fP + wid * 2048;

    const int qt = 15 - (int)blockIdx.x;      // large qt dispatched first
    const int q0 = qt * 128;
    const int nt = qt + 1;                    // number of 128-wide k-tiles
    const int qw = q0 + wid * 16;             // wave's first q row
    bf16x8 aq0 = *(const bf16x8*)&Qp[(size_t)(qw + (l & 15)) * DH_ + ((l >> 4) << 3)];
    bf16x8 aq1 = *(const bf16x8*)&Qp[(size_t)(qw + (l & 15)) * DH_ + 32 + ((l >> 4) << 3)];

    float mrow[4] = {-1e30f, -1e30f, -1e30f, -1e30f};
    float lrow[4] = {0.f, 0.f, 0.f, 0.f};
    f32x4 o[4] = {};

    short8 kA0 = *(const short8*)(Kp + kOff0);
    short8 kA1 = *(const short8*)(Kp + kOff1);
    short8 vA0 = *(const short8*)(Vp + vOff0);
    short8 vA1 = *(const short8*)(Vp + vOff1);

    for (int kt = 0; kt < nt; ++kt) {
        __syncthreads();
        *(short8*)ldsK0 = kA0;  *(short8*)ldsK1 = kA1;
        *(short8*)ldsV0 = vA0;  *(short8*)ldsV1 = vA1;
        __syncthreads();
        if (kt + 1 < nt) {
            const int nb = (kt + 1) * 128;
            kA0 = *(const short8*)(Kp + nb * DH_ + kOff0);
            kA1 = *(const short8*)(Kp + nb * DH_ + kOff1);
            vA0 = *(const short8*)(Vp + nb + vOff0);
            vA1 = *(const short8*)(Vp + nb + vOff1);
        }
        const bool diag = (kt == nt - 1);
        const int jtop = diag ? (wid | 1) : 7;
        const int ktop = diag ? (wid >> 1) : 3;

        f32x4 s[8] = {};
        __builtin_amdgcn_s_setprio(1);
        #pragma unroll
        for (int jk = 0; jk < 8; ++jk) if (jk <= jtop) {
            s[jk] = mfma16(aq0, *(const bf16x8*)(fK + (jk * 2 + 0) * 512 + l * 8), s[jk]);
            s[jk] = mfma16(aq1, *(const bf16x8*)(fK + (jk * 2 + 1) * 512 + l * 8), s[jk]);
        }
        __builtin_amdgcn_s_setprio(0);
        if (diag) {
            #pragma unroll
            for (int jk = 0; jk < 8; ++jk) if (jk <= jtop && jk >= wid) {
                #pragma unroll
                for (int r = 0; r < 4; ++r) {
                    int qr = wid * 16 + ((l >> 4) << 2) + r;
                    int kc = jk * 16 + (l & 15);
                    if (kc > qr) s[jk][r] = -1e30f;
                }
            }
        }
        float rm[4];
        #pragma unroll
        for (int r = 0; r < 4; ++r) {
            float m = -1e30f;
            #pragma unroll
            for (int jk = 0; jk < 8; ++jk) if (jk <= jtop) m = fmaxf(m, s[jk][r]);
            #pragma unroll
            for (int msk = 1; msk < 16; msk <<= 1) m = fmaxf(m, __shfl_xor(m, msk));
            rm[r] = m;
        }
        float need = fmaxf(fmaxf(rm[0] - mrow[0], rm[1] - mrow[1]),
                           fmaxf(rm[2] - mrow[2], rm[3] - mrow[3]));
        if (!__all(need <= 8.f)) {
            #pragma unroll
            for (int r = 0; r < 4; ++r) {
                float mn = fmaxf(mrow[r], rm[r]);
                float scl = __expf(mrow[r] - mn);
                mrow[r] = mn;  lrow[r] *= scl;
                #pragma unroll
                for (int jd = 0; jd < 4; ++jd) o[jd][r] *= scl;
            }
        }
        #pragma unroll
        for (int r = 0; r < 4; ++r) {
            float rs = 0.f;
            #pragma unroll
            for (int jk = 0; jk < 8; ++jk) if (jk <= jtop) {
                float p = __expf(s[jk][r] - mrow[r]);
                rs += p;
                fPw[(jk >> 1) * 512 + ((jk & 1) * 2 + ((l & 15) >> 3)) * 128 +
                    (((l >> 4) << 2) + r) * 8 + (l & 7)] = f2bf(p);
            }
            #pragma unroll
            for (int msk = 1; msk < 16; msk <<= 1) rs += __shfl_xor(rs, msk);
            lrow[r] += rs;
        }
        __builtin_amdgcn_s_setprio(1);
        #pragma unroll
        for (int kc2 = 0; kc2 < 4; ++kc2) if (kc2 <= ktop) {
            bf16x8 pa = *(const bf16x8*)(fPw + kc2 * 512 + l * 8);
            #pragma unroll
            for (int jd = 0; jd < 4; ++jd)
                o[jd] = mfma16(pa, *(const bf16x8*)(fV + (jd * 4 + kc2) * 512 + l * 8), o[jd]);
        }
        __builtin_amdgcn_s_setprio(0);
    }
    #pragma unroll
    for (int r = 0; r < 4; ++r) {
        float inv = 1.0f / lrow[r];
        int q = qw + ((l >> 4) << 2) + r;
        #pragma unroll
        for (int jd = 0; jd < 4; ++jd) {
            int d = jd * 16 + (l & 15);
            Zb[(((size_t)b * SS + q) * HH + h) * DH_ + d] = f2bf(o[jd][r] * inv);
        }
    }
}

// ---------------------------------------------------------------------------
// gemm_out: [4096,1024] @ [1024,1024] + b_O -> fp32
// ---------------------------------------------------------------------------
__global__ __launch_bounds__(256)
void gemm_out(const u16* __restrict__ Zb, const u16* __restrict__ WoT,
              const float* __restrict__ bO, float* __restrict__ out) {
    __shared__ __align__(16) u16 tA[128 * 64];
    __shared__ __align__(16) u16 tB[128 * 64];
    const int brow = blockIdx.x * 128, bcol = blockIdx.y * 128;
    const int t = threadIdx.x, wid = t >> 6, l = t & 63;
    const int wr = (wid >> 1) * 64, wc = (wid & 1) * 64;
    f32x4 acc[4][4] = {};
    for (int k0 = 0; k0 < DM_; k0 += 64) {
        __syncthreads();
        #pragma unroll
        for (int i = 0; i < 4; ++i) {
            const int off = i * 4096 + t * 16;
            const int row = off >> 7, colB = off & 127;
            gload16((const char*)Zb + ((size_t)(brow + row) * DM_ + k0) * 2 + colB,
                    (char*)tA + off);
            gload16((const char*)WoT + ((size_t)(bcol + row) * DM_ + k0) * 2 + colB,
                    (char*)tB + off);
        }
        __syncthreads();
        #pragma unroll
        for (int kc = 0; kc < 64; kc += 32) {
            bf16x8 a[4], b[4];
            #pragma unroll
            for (int i = 0; i < 4; ++i) a[i] = fragLd(tA, wr + i * 16, kc, 64);
            #pragma unroll
            for (int j = 0; j < 4; ++j) b[j] = fragLd(tB, wc + j * 16, kc, 64);
            #pragma unroll
            for (int i = 0; i < 4; ++i)
                #pragma unroll
                for (int j = 0; j < 4; ++j)
                    acc[i][j] = mfma16(a[i], b[j], acc[i][j]);
        }
    }
    #pragma unroll
    for (int i = 0; i < 4; ++i)
        #pragma unroll
        for (int j = 0; j < 4; ++j)
            #pragma unroll
            for (int r = 0; r < 4; ++r) {
                int row = brow + wr + i * 16 + ((l >> 4) << 2) + r;
                int col = bcol + wc + j * 16 + (l & 15);
                out[(size_t)row * DM_ + col] = acc[i][j][r] + bO[col];
            }
}

// ---------------------------------------------------------------------------
extern "C" void kernel_launch(void* const* d_in, const int* in_sizes, int n_in,
                              void* d_out, int out_size, void* d_ws, size_t ws_size,
                              hipStream_t stream) {
    const float* x  = (const float*)d_in[0];
    const float* wq = (const float*)d_in[1];
    const float* wk = (const float*)d_in[2];
    const float* wv = (const float*)d_in[3];
    const float* wo = (const float*)d_in[4];
    const float* bq = (const float*)d_in[5];
    const float* bk = (const float*)d_in[6];
    const float* bv = (const float*)d_in[7];
    const float* bO = (const float*)d_in[8];
    float* out = (float*)d_out;

    char* w = (char*)d_ws;
    u16* Xb  = (u16*)w;  w += (size_t)NROW * DM_ * 2;
    u16* Wt  = (u16*)w;  w += (size_t)NQKV * DM_ * 2;
    u16* WoT = (u16*)w;  w += (size_t)DM_ * DM_ * 2;
    float* biasQKV = (float*)w; w += (size_t)NQKV * 4;
    u16* Qs  = (u16*)w;  w += (size_t)BB * HH * SS * DH_ * 2;
    u16* Ks  = (u16*)w;  w += (size_t)BB * HH * SS * DH_ * 2;
    u16* Vt  = (u16*)w;  w += (size_t)BB * HH * SS * DH_ * 2;
    u16* Zb  = (u16*)w;  w += (size_t)BB * HH * SS * DH_ * 2;

    pack_x<<<512, 256, 0, stream>>>(x, bq, bk, bv, Xb, biasQKV);
    trans_w<<<dim3(16, 48), 256, 0, stream>>>(wq, wk, wv, Wt);
    trans_wo<<<dim3(16, 16), 256, 0, stream>>>(wo, WoT);
    gemm_qk<<<dim3(NROW / 128, 16), 256, 0, stream>>>(Xb, Wt, biasQKV, Qs, Ks);
    gemm_v<<<dim3(8, NROW / 128), 256, 0, stream>>>(Wt + (size_t)2048 * DM_, Xb,
                                                    biasQKV + 2048, Vt);
    attn_fwd<<<dim3(16, BB * HH), 512, 0, stream>>>(Qs, Ks, Vt, Zb);
    gemm_out<<<dim3(NROW / 128, DM_ / 128), 256, 0, stream>>>(Zb, WoT, bO, out);
}

// Round 5
// 157.518 us; speedup vs baseline: 1.1107x; 1.1107x over previous
//
#include <hip/hip_runtime.h>
#include <hip/hip_bf16.h>

// Sizes for this problem instance
#define BB   2
#define SS   2048
#define HH   16
#define DM_  1024
#define DH_  64
#define NROW 4096   // BB*SS
#define NQKV 3072   // 3 * HH * DH

typedef unsigned short u16;
using short4v = __attribute__((ext_vector_type(4))) short;
using short8 = __attribute__((ext_vector_type(8))) short;
using bf16x8 = __attribute__((ext_vector_type(8))) __bf16;
using f32x4  = __attribute__((ext_vector_type(4))) float;

// Q pre-scale: 1/sqrt(64) * 1/ln(2)  (so attention uses exp2 directly)
#define QSCALE 0.180336880f

__device__ __forceinline__ u16 f2bf(float f) {
    union { float f; unsigned u; } v; v.f = f;
    unsigned r = v.u + 0x7fffu + ((v.u >> 16) & 1u);
    return (u16)(r >> 16);
}
// cheap round-half-up (for P values only; always positive, 0.5 ulp worst case)
__device__ __forceinline__ u16 f2bf_fast(float f) {
    union { float f; unsigned u; } v; v.f = f;
    return (u16)((v.u + 0x8000u) >> 16);
}

__device__ __forceinline__ f32x4 mfma16(bf16x8 a, bf16x8 b, f32x4 c) {
    return __builtin_amdgcn_mfma_f32_16x16x32_bf16(a, b, c, 0, 0, 0);
}

// lane l, elem j -> (row = rowOff + (l&15), k = kOff + (l>>4)*8 + j)
__device__ __forceinline__ bf16x8 fragLd(const u16* base, int rowOff, int kOff, int ld) {
    const int l = threadIdx.x & 63;
    return *(const bf16x8*)(base + (rowOff + (l & 15)) * ld + kOff + ((l >> 4) << 3));
}

// async global->LDS, 16B per lane (dest = wave-uniform base + lane*16)
__device__ __forceinline__ void gload16(const void* g, void* l) {
    __builtin_amdgcn_global_load_lds(
        (const __attribute__((address_space(1))) void*)g,
        (__attribute__((address_space(3))) void*)l, 16, 0, 0);
}

// ---------------------------------------------------------------------------
// prep: fused pack_x (vectorized) + trans_w + trans_wo + bias pack
// blocks 0..511 pack X; 512..1279 transpose W_QKV; 1280..1535 transpose W_O
// ---------------------------------------------------------------------------
__global__ __launch_bounds__(256)
void prep(const float* __restrict__ x,  const float* __restrict__ wq,
          const float* __restrict__ wk, const float* __restrict__ wv,
          const float* __restrict__ wo, const float* __restrict__ bq,
          const float* __restrict__ bk, const float* __restrict__ bv,
          u16* __restrict__ Xb, u16* __restrict__ Wt,
          u16* __restrict__ WoT, float* __restrict__ biasQKV) {
    __shared__ float tile[64][65];
    const int bx = blockIdx.x, t = threadIdx.x;
    if (bx < 512) {
        const int tid = bx * 256 + t;               // 131072 threads
        #pragma unroll
        for (int it = 0; it < 8; ++it) {            // 1048576 float4s
            int i = tid + it * 131072;
            float4 v = ((const float4*)x)[i];
            u16 b4[4] = {f2bf(v.x), f2bf(v.y), f2bf(v.z), f2bf(v.w)};
            ((short4v*)Xb)[i] = *(short4v*)b4;
        }
        if (tid < NQKV) {
            int mat = tid >> 10, h = (tid >> 6) & 15, d = tid & 63;
            const float* bb = (mat == 0) ? bq : ((mat == 1) ? bk : bv);
            biasQKV[tid] = bb[h * DH_ + d];
        }
    } else if (bx < 1280) {
        const int idx = bx - 512;                   // 768 blocks
        const int m0 = (idx & 15) * 64, hm = idx >> 4;
        const int mat = hm >> 4, h = hm & 15;
        const float* w = (mat == 0) ? wq : ((mat == 1) ? wk : wv);
        #pragma unroll
        for (int it = 0; it < 4; ++it) {
            int row = it * 16 + (t >> 4), c4 = (t & 15) * 4;
            float4 v = *(const float4*)&w[((size_t)h * 1024 + m0 + row) * 64 + c4];
            tile[row][c4] = v.x; tile[row][c4 + 1] = v.y;
            tile[row][c4 + 2] = v.z; tile[row][c4 + 3] = v.w;
        }
        __syncthreads();
        #pragma unroll
        for (int it = 0; it < 2; ++it) {
            int c = it * 256 + t, d = c >> 3, mc = (c & 7) * 8;
            u16 buf[8];
            #pragma unroll
            for (int j = 0; j < 8; ++j) buf[j] = f2bf(tile[mc + j][d]);
            *(short8*)&Wt[((size_t)(mat * 1024 + h * 64 + d)) * 1024 + m0 + mc] = *(short8*)buf;
        }
    } else {
        const int idx = bx - 1280;                  // 256 blocks
        const int n0 = (idx & 15) * 64, k0 = (idx >> 4) * 64;
        #pragma unroll
        for (int it = 0; it < 4; ++it) {
            int row = it * 16 + (t >> 4), c4 = (t & 15) * 4;
            float4 v = *(const float4*)&wo[(size_t)(k0 + row) * DM_ + n0 + c4];
            tile[row][c4] = v.x; tile[row][c4 + 1] = v.y;
            tile[row][c4 + 2] = v.z; tile[row][c4 + 3] = v.w;
        }
        __syncthreads();
        #pragma unroll
        for (int it = 0; it < 2; ++it) {
            int c = it * 256 + t, n = c >> 3, kc = (c & 7) * 8;
            u16 buf[8];
            #pragma unroll
            for (int j = 0; j < 8; ++j) buf[j] = f2bf(tile[kc + j][n]);
            *(short8*)&WoT[(size_t)(n0 + n) * DM_ + k0 + kc] = *(short8*)buf;
        }
    }
}

// ---------------------------------------------------------------------------
// gemm_qkv2: fused. blocks 0..511: [4096,1024]@[1024,2048] -> Q(scaled),K
//                   blocks 512..767: Vt = WtV @ Xb^T -> Vt[b*1024+n][s]
// ---------------------------------------------------------------------------
__global__ __launch_bounds__(256)
void gemm_qkv2(const u16* __restrict__ Xb, const u16* __restrict__ Wt,
               const float* __restrict__ bias, u16* __restrict__ Qs,
               u16* __restrict__ Ks, u16* __restrict__ Vt) {
    __shared__ __align__(16) u16 tA[128 * 64];
    __shared__ __align__(16) u16 tB[128 * 64];
    const int bx = blockIdx.x;
    const int t = threadIdx.x, wid = t >> 6, l = t & 63;
    const int wr = (wid >> 1) * 64, wc = (wid & 1) * 64;
    f32x4 acc[4][4] = {};
    const bool isV = (bx >= 512);
    const u16* Ap; const u16* Bp; int brow, bcol;
    if (!isV) { brow = (bx & 31) * 128; bcol = (bx >> 5) * 128; Ap = Xb; Bp = Wt; }
    else { int i2 = bx - 512; brow = (i2 & 7) * 128; bcol = (i2 >> 3) * 128;
           Ap = Wt + (size_t)2048 * DM_; Bp = Xb; }
    for (int k0 = 0; k0 < DM_; k0 += 64) {
        __syncthreads();
        #pragma unroll
        for (int i = 0; i < 4; ++i) {
            const int off = i * 4096 + t * 16;
            const int row = off >> 7, colB = off & 127;
            gload16((const char*)Ap + ((size_t)(brow + row) * DM_ + k0) * 2 + colB,
                    (char*)tA + off);
            gload16((const char*)Bp + ((size_t)(bcol + row) * DM_ + k0) * 2 + colB,
                    (char*)tB + off);
        }
        __syncthreads();
        #pragma unroll
        for (int kc = 0; kc < 64; kc += 32) {
            bf16x8 a[4], b[4];
            #pragma unroll
            for (int i = 0; i < 4; ++i) a[i] = fragLd(tA, wr + i * 16, kc, 64);
            #pragma unroll
            for (int j = 0; j < 4; ++j) b[j] = fragLd(tB, wc + j * 16, kc, 64);
            #pragma unroll
            for (int i = 0; i < 4; ++i)
                #pragma unroll
                for (int j = 0; j < 4; ++j)
                    acc[i][j] = mfma16(a[i], b[j], acc[i][j]);
        }
    }
    if (!isV) {
        #pragma unroll
        for (int i = 0; i < 4; ++i)
            #pragma unroll
            for (int j = 0; j < 4; ++j)
                #pragma unroll
                for (int r = 0; r < 4; ++r) {
                    int row = brow + wr + i * 16 + ((l >> 4) << 2) + r;
                    int col = bcol + wc + j * 16 + (l & 15);
                    float v = acc[i][j][r] + bias[col];
                    int h = (col >> 6) & 15, d = col & 63;
                    int b = row >> 11, s = row & 2047;
                    size_t adr = (((size_t)(b * HH + h)) * SS + s) * DH_ + d;
                    if (col < 1024) Qs[adr] = f2bf(v * QSCALE);
                    else            Ks[adr] = f2bf(v);
                }
    } else {
        #pragma unroll
        for (int i = 0; i < 4; ++i)
            #pragma unroll
            for (int j = 0; j < 4; ++j)
                #pragma unroll
                for (int r = 0; r < 4; ++r) {
                    int row = brow + wr + i * 16 + ((l >> 4) << 2) + r;  // n'=h*64+d
                    int col = bcol + wc + j * 16 + (l & 15);             // s_glob
                    float v = acc[i][j][r] + bias[2048 + row];
                    int b = col >> 11, s = col & 2047;
                    Vt[((size_t)(b * 1024 + row)) * SS + s] = f2bf(v);
                }
    }
}

// ---------------------------------------------------------------------------
// attn: flash attention, QBLK=64 (4 waves), KVBLK=128, fragment-linear LDS,
// reg-prefetch, static-max softmax (exp2 direct, no running max, deferred
// l-reduction). Blocks pair q-tiles (i, 31-i): uniform 17 K-tiles/block,
// 512 blocks -> 2 blocks/CU co-resident.
// ---------------------------------------------------------------------------
__global__ __launch_bounds__(256)
void attn_fwd(const u16* __restrict__ Qs, const u16* __restrict__ Ks,
              const u16* __restrict__ Vt, u16* __restrict__ Zb) {
    __shared__ __align__(16) u16 fK[8192];   // 128 kseq x 64 d  (16 KiB)
    __shared__ __align__(16) u16 fV[8192];   // 64 d x 128 kseq  (16 KiB)
    __shared__ __align__(16) u16 fP[8192];   // 4 waves x 16 q x 128 k (16 KiB)
    const int bh = blockIdx.y, b = bh >> 4, h = bh & 15;
    const int t = threadIdx.x, wid = t >> 6, l = t & 63;
    const u16* Qp = Qs + (size_t)bh * SS * DH_;
    const u16* Kp = Ks + (size_t)bh * SS * DH_;
    const u16* Vp = Vt + (size_t)bh * DH_ * SS;

    // staging: thread t owns chunks c = t + 256*i, i=0..3 (1024 chunks of 8 u16)
    int kOff[4]; size_t vOff[4]; u16 *ldsK[4], *ldsV[4];
    #pragma unroll
    for (int i = 0; i < 4; ++i) {
        const int c = t + 256 * i;
        kOff[i] = (((c >> 7) << 4) + (c & 15)) * DH_ + ((c >> 6) & 1) * 32 + ((c >> 4) & 3) * 8;
        vOff[i] = (size_t)(((c >> 8) << 4) + (c & 15)) * SS + ((c >> 6) & 3) * 32 + ((c >> 4) & 3) * 8;
        ldsK[i] = fK + c * 8;
        ldsV[i] = fV + c * 8;
    }
    u16* fPw = fP + wid * 2048;

    // prefetch phase-0 tile-0
    short8 kA[4], vA[4];
    #pragma unroll
    for (int i = 0; i < 4; ++i) {
        kA[i] = *(const short8*)(Kp + kOff[i]);
        vA[i] = *(const short8*)(Vp + vOff[i]);
    }

    #pragma unroll
    for (int ph = 0; ph < 2; ++ph) {
        const int qt = ph ? (31 - (int)blockIdx.x) : (int)blockIdx.x;
        const int nt = (qt >> 1) + 1;          // K-tiles of 128
        const int qw = qt * 64 + wid * 16;     // wave's first q row
        bf16x8 aq0 = *(const bf16x8*)&Qp[(size_t)(qw + (l & 15)) * DH_ + ((l >> 4) << 3)];
        bf16x8 aq1 = *(const bf16x8*)&Qp[(size_t)(qw + (l & 15)) * DH_ + 32 + ((l >> 4) << 3)];

        float lrow[4] = {0.f, 0.f, 0.f, 0.f};
        f32x4 o[4] = {};

        for (int kt = 0; kt < nt; ++kt) {
            const int kv0 = kt * 128;
            __syncthreads();                   // prev tile's readers done
            #pragma unroll
            for (int i = 0; i < 4; ++i) { *(short8*)ldsK[i] = kA[i]; *(short8*)ldsV[i] = vA[i]; }
            __syncthreads();                   // staged data visible
            const bool more = (kt + 1 < nt);
            if (more || ph == 0) {             // prefetch next tile (or ph1 tile0)
                const int nb = more ? (kt + 1) * 128 : 0;
                #pragma unroll
                for (int i = 0; i < 4; ++i) {
                    kA[i] = *(const short8*)(Kp + (size_t)nb * DH_ + kOff[i]);
                    vA[i] = *(const short8*)(Vp + nb + vOff[i]);
                }
            }
            const bool diag = (kt == nt - 1);
            const int jtop = diag ? min(7, ((qw + 15 - kv0) >> 4) | 1) : 7;

            f32x4 s[8] = {};
            __builtin_amdgcn_s_setprio(1);
            #pragma unroll
            for (int jk = 0; jk < 8; ++jk) if (jk <= jtop) {
                s[jk] = mfma16(aq0, *(const bf16x8*)(fK + (jk * 2 + 0) * 512 + l * 8), s[jk]);
                s[jk] = mfma16(aq1, *(const bf16x8*)(fK + (jk * 2 + 1) * 512 + l * 8), s[jk]);
            }
            __builtin_amdgcn_s_setprio(0);
            if (diag) {                        // causal mask, global indices
                #pragma unroll
                for (int jk = 0; jk < 8; ++jk) if (jk <= jtop) {
                    const int kg = kv0 + jk * 16 + (l & 15);
                    #pragma unroll
                    for (int r = 0; r < 4; ++r) {
                        const int qg = qw + ((l >> 4) << 2) + r;
                        if (kg > qg) s[jk][r] = -1e30f;
                    }
                }
            }
            // p = exp2(s) directly (Q pre-scaled by 1/(8 ln2)); defer l-reduce
            #pragma unroll
            for (int r = 0; r < 4; ++r) {
                #pragma unroll
                for (int jk = 0; jk < 8; ++jk) if (jk <= jtop) {
                    float p = exp2f(s[jk][r]);
                    lrow[r] += p;
                    fPw[(jk >> 1) * 512 + ((jk & 1) * 2 + ((l & 15) >> 3)) * 128 +
                        (((l >> 4) << 2) + r) * 8 + (l & 7)] = f2bf_fast(p);
                }
            }
            __builtin_amdgcn_s_setprio(1);
            #pragma unroll
            for (int kc2 = 0; kc2 < 4; ++kc2) if (kc2 <= (jtop >> 1)) {
                bf16x8 pa = *(const bf16x8*)(fPw + kc2 * 512 + l * 8);
                #pragma unroll
                for (int jd = 0; jd < 4; ++jd)
                    o[jd] = mfma16(pa, *(const bf16x8*)(fV + (jd * 4 + kc2) * 512 + l * 8), o[jd]);
            }
            __builtin_amdgcn_s_setprio(0);
        }
        // final l reduction across the 16 lanes holding this row's k-slices
        #pragma unroll
        for (int r = 0; r < 4; ++r) {
            #pragma unroll
            for (int msk = 1; msk < 16; msk <<= 1) lrow[r] += __shfl_xor(lrow[r], msk);
            const float inv = 1.0f / lrow[r];
            const int q = qw + ((l >> 4) << 2) + r;
            #pragma unroll
            for (int jd = 0; jd < 4; ++jd) {
                const int d = jd * 16 + (l & 15);
                Zb[(((size_t)b * SS + q) * HH + h) * DH_ + d] = f2bf(o[jd][r] * inv);
            }
        }
    }
}

// ---------------------------------------------------------------------------
// gemm_out: [4096,1024] @ [1024,1024] + b_O -> fp32
// ---------------------------------------------------------------------------
__global__ __launch_bounds__(256)
void gemm_out(const u16* __restrict__ Zb, const u16* __restrict__ WoT,
              const float* __restrict__ bO, float* __restrict__ out) {
    __shared__ __align__(16) u16 tA[128 * 64];
    __shared__ __align__(16) u16 tB[128 * 64];
    const int brow = blockIdx.x * 128, bcol = blockIdx.y * 128;
    const int t = threadIdx.x, wid = t >> 6, l = t & 63;
    const int wr = (wid >> 1) * 64, wc = (wid & 1) * 64;
    f32x4 acc[4][4] = {};
    for (int k0 = 0; k0 < DM_; k0 += 64) {
        __syncthreads();
        #pragma unroll
        for (int i = 0; i < 4; ++i) {
            const int off = i * 4096 + t * 16;
            const int row = off >> 7, colB = off & 127;
            gload16((const char*)Zb + ((size_t)(brow + row) * DM_ + k0) * 2 + colB,
                    (char*)tA + off);
            gload16((const char*)WoT + ((size_t)(bcol + row) * DM_ + k0) * 2 + colB,
                    (char*)tB + off);
        }
        __syncthreads();
        #pragma unroll
        for (int kc = 0; kc < 64; kc += 32) {
            bf16x8 a[4], b[4];
            #pragma unroll
            for (int i = 0; i < 4; ++i) a[i] = fragLd(tA, wr + i * 16, kc, 64);
            #pragma unroll
            for (int j = 0; j < 4; ++j) b[j] = fragLd(tB, wc + j * 16, kc, 64);
            #pragma unroll
            for (int i = 0; i < 4; ++i)
                #pragma unroll
                for (int j = 0; j < 4; ++j)
                    acc[i][j] = mfma16(a[i], b[j], acc[i][j]);
        }
    }
    #pragma unroll
    for (int i = 0; i < 4; ++i)
        #pragma unroll
        for (int j = 0; j < 4; ++j)
            #pragma unroll
            for (int r = 0; r < 4; ++r) {
                int row = brow + wr + i * 16 + ((l >> 4) << 2) + r;
                int col = bcol + wc + j * 16 + (l & 15);
                out[(size_t)row * DM_ + col] = acc[i][j][r] + bO[col];
            }
}

// ---------------------------------------------------------------------------
extern "C" void kernel_launch(void* const* d_in, const int* in_sizes, int n_in,
                              void* d_out, int out_size, void* d_ws, size_t ws_size,
                              hipStream_t stream) {
    const float* x  = (const float*)d_in[0];
    const float* wq = (const float*)d_in[1];
    const float* wk = (const float*)d_in[2];
    const float* wv = (const float*)d_in[3];
    const float* wo = (const float*)d_in[4];
    const float* bq = (const float*)d_in[5];
    const float* bk = (const float*)d_in[6];
    const float* bv = (const float*)d_in[7];
    const float* bO = (const float*)d_in[8];
    float* out = (float*)d_out;

    char* w = (char*)d_ws;
    u16* Xb  = (u16*)w;  w += (size_t)NROW * DM_ * 2;
    u16* Wt  = (u16*)w;  w += (size_t)NQKV * DM_ * 2;
    u16* WoT = (u16*)w;  w += (size_t)DM_ * DM_ * 2;
    float* biasQKV = (float*)w; w += (size_t)NQKV * 4;
    u16* Qs  = (u16*)w;  w += (size_t)BB * HH * SS * DH_ * 2;
    u16* Ks  = (u16*)w;  w += (size_t)BB * HH * SS * DH_ * 2;
    u16* Vt  = (u16*)w;  w += (size_t)BB * HH * SS * DH_ * 2;
    u16* Zb  = (u16*)w;  w += (size_t)BB * HH * SS * DH_ * 2;

    prep<<<1536, 256, 0, stream>>>(x, wq, wk, wv, wo, bq, bk, bv,
                                   Xb, Wt, WoT, biasQKV);
    gemm_qkv2<<<768, 256, 0, stream>>>(Xb, Wt, biasQKV, Qs, Ks, Vt);
    attn_fwd<<<dim3(16, BB * HH), 256, 0, stream>>>(Qs, Ks, Vt, Zb);
    gemm_out<<<dim3(NROW / 128, DM_ / 128), 256, 0, stream>>>(Zb, WoT, bO, out);
}

// Round 6
// 134.563 us; speedup vs baseline: 1.3002x; 1.1706x over previous
//
#include <hip/hip_runtime.h>
#include <hip/hip_bf16.h>

// Sizes for this problem instance
#define BB   2
#define SS   2048
#define HH   16
#define DM_  1024
#define DH_  64
#define NROW 4096   // BB*SS
#define NQKV 3072   // 3 * HH * DH

typedef unsigned short u16;
typedef unsigned int u32;
using short4v = __attribute__((ext_vector_type(4))) short;
using short8 = __attribute__((ext_vector_type(8))) short;
using bf16x8 = __attribute__((ext_vector_type(8))) __bf16;
using f32x4  = __attribute__((ext_vector_type(4))) float;
using f32x16 = __attribute__((ext_vector_type(16))) float;

// Q pre-scale: 1/sqrt(64) * 1/ln(2)  (so attention uses exp2 directly)
#define QSCALE 0.180336880f

__device__ __forceinline__ u16 f2bf(float f) {
    union { float f; unsigned u; } v; v.f = f;
    unsigned r = v.u + 0x7fffu + ((v.u >> 16) & 1u);
    return (u16)(r >> 16);
}

__device__ __forceinline__ f32x4 mfma16(bf16x8 a, bf16x8 b, f32x4 c) {
    return __builtin_amdgcn_mfma_f32_16x16x32_bf16(a, b, c, 0, 0, 0);
}
__device__ __forceinline__ f32x16 mfma32(bf16x8 a, bf16x8 b, f32x16 c) {
    return __builtin_amdgcn_mfma_f32_32x32x16_bf16(a, b, c, 0, 0, 0);
}

__device__ __forceinline__ u32 cvtpk(float lo, float hi) {
    u32 r;
    asm("v_cvt_pk_bf16_f32 %0, %1, %2" : "=v"(r) : "v"(lo), "v"(hi));
    return r;
}
// swaps a[32:63] <-> b[0:31]:  a' = {a_lo, b_lo@lo-lanes}, b' = {a_hi@hi-lanes, b_hi}
#define PLSWAP(a, b) asm("v_permlane32_swap_b32 %0, %1" : "+v"(a), "+v"(b))

// lane l, elem j -> (row = rowOff + (l&15), k = kOff + (l>>4)*8 + j)
__device__ __forceinline__ bf16x8 fragLd(const u16* base, int rowOff, int kOff, int ld) {
    const int l = threadIdx.x & 63;
    return *(const bf16x8*)(base + (rowOff + (l & 15)) * ld + kOff + ((l >> 4) << 3));
}

// async global->LDS, 16B per lane (dest = wave-uniform base + lane*16)
__device__ __forceinline__ void gload16(const void* g, void* l) {
    __builtin_amdgcn_global_load_lds(
        (const __attribute__((address_space(1))) void*)g,
        (__attribute__((address_space(3))) void*)l, 16, 0, 0);
}

// ---------------------------------------------------------------------------
// prep: fused pack_x (vectorized) + trans_w + trans_wo + bias pack
// ---------------------------------------------------------------------------
__global__ __launch_bounds__(256)
void prep(const float* __restrict__ x,  const float* __restrict__ wq,
          const float* __restrict__ wk, const float* __restrict__ wv,
          const float* __restrict__ wo, const float* __restrict__ bq,
          const float* __restrict__ bk, const float* __restrict__ bv,
          u16* __restrict__ Xb, u16* __restrict__ Wt,
          u16* __restrict__ WoT, float* __restrict__ biasQKV) {
    __shared__ float tile[64][65];
    const int bx = blockIdx.x, t = threadIdx.x;
    if (bx < 512) {
        const int tid = bx * 256 + t;
        #pragma unroll
        for (int it = 0; it < 8; ++it) {
            int i = tid + it * 131072;
            float4 v = ((const float4*)x)[i];
            u16 b4[4] = {f2bf(v.x), f2bf(v.y), f2bf(v.z), f2bf(v.w)};
            ((short4v*)Xb)[i] = *(short4v*)b4;
        }
        if (tid < NQKV) {
            int mat = tid >> 10, h = (tid >> 6) & 15, d = tid & 63;
            const float* bb = (mat == 0) ? bq : ((mat == 1) ? bk : bv);
            biasQKV[tid] = bb[h * DH_ + d];
        }
    } else if (bx < 1280) {
        const int idx = bx - 512;
        const int m0 = (idx & 15) * 64, hm = idx >> 4;
        const int mat = hm >> 4, h = hm & 15;
        const float* w = (mat == 0) ? wq : ((mat == 1) ? wk : wv);
        #pragma unroll
        for (int it = 0; it < 4; ++it) {
            int row = it * 16 + (t >> 4), c4 = (t & 15) * 4;
            float4 v = *(const float4*)&w[((size_t)h * 1024 + m0 + row) * 64 + c4];
            tile[row][c4] = v.x; tile[row][c4 + 1] = v.y;
            tile[row][c4 + 2] = v.z; tile[row][c4 + 3] = v.w;
        }
        __syncthreads();
        #pragma unroll
        for (int it = 0; it < 2; ++it) {
            int c = it * 256 + t, d = c >> 3, mc = (c & 7) * 8;
            u16 buf[8];
            #pragma unroll
            for (int j = 0; j < 8; ++j) buf[j] = f2bf(tile[mc + j][d]);
            *(short8*)&Wt[((size_t)(mat * 1024 + h * 64 + d)) * 1024 + m0 + mc] = *(short8*)buf;
        }
    } else {
        const int idx = bx - 1280;
        const int n0 = (idx & 15) * 64, k0 = (idx >> 4) * 64;
        #pragma unroll
        for (int it = 0; it < 4; ++it) {
            int row = it * 16 + (t >> 4), c4 = (t & 15) * 4;
            float4 v = *(const float4*)&wo[(size_t)(k0 + row) * DM_ + n0 + c4];
            tile[row][c4] = v.x; tile[row][c4 + 1] = v.y;
            tile[row][c4 + 2] = v.z; tile[row][c4 + 3] = v.w;
        }
        __syncthreads();
        #pragma unroll
        for (int it = 0; it < 2; ++it) {
            int c = it * 256 + t, n = c >> 3, kc = (c & 7) * 8;
            u16 buf[8];
            #pragma unroll
            for (int j = 0; j < 8; ++j) buf[j] = f2bf(tile[kc + j][n]);
            *(short8*)&WoT[(size_t)(n0 + n) * DM_ + k0 + kc] = *(short8*)buf;
        }
    }
}

// ---------------------------------------------------------------------------
// gemm_qkv2: fused. blocks 0..511: [4096,1024]@[1024,2048] -> Q(scaled),K
//                   blocks 512..767: Vt = WtV @ Xb^T -> Vt[b*1024+n][s]
// ---------------------------------------------------------------------------
__global__ __launch_bounds__(256)
void gemm_qkv2(const u16* __restrict__ Xb, const u16* __restrict__ Wt,
               const float* __restrict__ bias, u16* __restrict__ Qs,
               u16* __restrict__ Ks, u16* __restrict__ Vt) {
    __shared__ __align__(16) u16 tA[128 * 64];
    __shared__ __align__(16) u16 tB[128 * 64];
    const int bx = blockIdx.x;
    const int t = threadIdx.x, wid = t >> 6, l = t & 63;
    const int wr = (wid >> 1) * 64, wc = (wid & 1) * 64;
    f32x4 acc[4][4] = {};
    const bool isV = (bx >= 512);
    const u16* Ap; const u16* Bp; int brow, bcol;
    if (!isV) { brow = (bx & 31) * 128; bcol = (bx >> 5) * 128; Ap = Xb; Bp = Wt; }
    else { int i2 = bx - 512; brow = (i2 & 7) * 128; bcol = (i2 >> 3) * 128;
           Ap = Wt + (size_t)2048 * DM_; Bp = Xb; }
    for (int k0 = 0; k0 < DM_; k0 += 64) {
        __syncthreads();
        #pragma unroll
        for (int i = 0; i < 4; ++i) {
            const int off = i * 4096 + t * 16;
            const int row = off >> 7, colB = off & 127;
            gload16((const char*)Ap + ((size_t)(brow + row) * DM_ + k0) * 2 + colB,
                    (char*)tA + off);
            gload16((const char*)Bp + ((size_t)(bcol + row) * DM_ + k0) * 2 + colB,
                    (char*)tB + off);
        }
        __syncthreads();
        #pragma unroll
        for (int kc = 0; kc < 64; kc += 32) {
            bf16x8 a[4], b[4];
            #pragma unroll
            for (int i = 0; i < 4; ++i) a[i] = fragLd(tA, wr + i * 16, kc, 64);
            #pragma unroll
            for (int j = 0; j < 4; ++j) b[j] = fragLd(tB, wc + j * 16, kc, 64);
            #pragma unroll
            for (int i = 0; i < 4; ++i)
                #pragma unroll
                for (int j = 0; j < 4; ++j)
                    acc[i][j] = mfma16(a[i], b[j], acc[i][j]);
        }
    }
    if (!isV) {
        #pragma unroll
        for (int i = 0; i < 4; ++i)
            #pragma unroll
            for (int j = 0; j < 4; ++j)
                #pragma unroll
                for (int r = 0; r < 4; ++r) {
                    int row = brow + wr + i * 16 + ((l >> 4) << 2) + r;
                    int col = bcol + wc + j * 16 + (l & 15);
                    float v = acc[i][j][r] + bias[col];
                    int h = (col >> 6) & 15, d = col & 63;
                    int b = row >> 11, s = row & 2047;
                    size_t adr = (((size_t)(b * HH + h)) * SS + s) * DH_ + d;
                    if (col < 1024) Qs[adr] = f2bf(v * QSCALE);
                    else            Ks[adr] = f2bf(v);
                }
    } else {
        #pragma unroll
        for (int i = 0; i < 4; ++i)
            #pragma unroll
            for (int j = 0; j < 4; ++j)
                #pragma unroll
                for (int r = 0; r < 4; ++r) {
                    int row = brow + wr + i * 16 + ((l >> 4) << 2) + r;
                    int col = bcol + wc + j * 16 + (l & 15);
                    float v = acc[i][j][r] + bias[2048 + row];
                    int b = col >> 11, s = col & 2047;
                    Vt[((size_t)(b * 1024 + row)) * SS + s] = f2bf(v);
                }
    }
}

// ---------------------------------------------------------------------------
// attn: swapped-QK 32x32 MFMA flash attention (m214/T12 structure).
// 4 warps x 32 q-rows (QBLK=128), KVBLK=64. Lane holds P for ONE q-row ->
// softmax fully in-register; P->PV A-frags via cvt_pk + permlane32_swap.
// Fragment-linear fK/fV (conflict-free b128). Reg-prefetch. 512 blocks,
// largest-qt-first (LPT balance), ~2 blocks/CU.
// ---------------------------------------------------------------------------
__global__ __launch_bounds__(256)
void attn_fwd(const u16* __restrict__ Qs, const u16* __restrict__ Ks,
              const u16* __restrict__ Vt, u16* __restrict__ Zb) {
    __shared__ __align__(16) u16 fK[4096];   // 64 kseq x 64 d, fragment-linear (8 KiB)
    __shared__ __align__(16) u16 fV[4096];   // 64 d x 64 kseq, fragment-linear (8 KiB)
    __shared__ float lrL[128];               // per-warp row sums
    const int bidx = blockIdx.x;
    const int qt = 15 - (bidx >> 5);         // largest first
    const int bh = bidx & 31, b = bh >> 4, h = bh & 15;
    const int t = threadIdx.x, wid = t >> 6, l = t & 63;
    const int hi = l >> 5, c32 = l & 31;
    const u16* Qp = Qs + (size_t)bh * SS * DH_;
    const u16* Kp = Ks + (size_t)bh * SS * DH_;
    const u16* Vp = Vt + (size_t)bh * DH_ * SS;
    const int q0 = qt * 128;
    const int qw = q0 + wid * 32;            // warp's first q row
    const int nt = 2 * qt + 2;               // 64-wide K-tiles

    // Q B-fragments: aq[dk] -> col q = qw + (l&31), k(d) = dk*16 + hi*8 + j
    bf16x8 aq[4];
    #pragma unroll
    for (int dk = 0; dk < 4; ++dk)
        aq[dk] = *(const bf16x8*)&Qp[(size_t)(qw + c32) * DH_ + dk * 16 + hi * 8];

    // staging: thread t owns chunks c = t, t+256  (512 chunks of 8 u16 per tile)
    int kOff[2]; size_t vOff[2]; u16 *dK[2], *dV[2];
    #pragma unroll
    for (int i = 0; i < 2; ++i) {
        const int c = t + 256 * i, sec = c >> 6, ln = c & 63;
        kOff[i] = ((sec >> 2) * 32 + (ln & 31)) * DH_ + (sec & 3) * 16 + (ln >> 5) * 8;
        vOff[i] = (size_t)((sec >> 2) * 32 + (ln & 31)) * SS + (sec & 3) * 16 + (ln >> 5) * 8;
        dK[i] = fK + c * 8;
        dV[i] = fV + c * 8;
    }

    short8 kA[2], vA[2];
    #pragma unroll
    for (int i = 0; i < 2; ++i) {
        kA[i] = *(const short8*)(Kp + kOff[i]);
        vA[i] = *(const short8*)(Vp + vOff[i]);
    }

    f32x16 o0 = {}, o1 = {};
    float lrow = 0.f;

    for (int kt = 0; kt < nt; ++kt) {
        const int kv0 = kt * 64;
        __syncthreads();                     // prev tile's readers done
        *(short8*)dK[0] = kA[0]; *(short8*)dK[1] = kA[1];
        *(short8*)dV[0] = vA[0]; *(short8*)dV[1] = vA[1];
        __syncthreads();                     // staged data visible
        if (kt + 1 < nt) {                   // reg-prefetch next tile
            const int nb = (kt + 1) * 64;
            #pragma unroll
            for (int i = 0; i < 2; ++i) {
                kA[i] = *(const short8*)(Kp + (size_t)nb * DH_ + kOff[i]);
                vA[i] = *(const short8*)(Vp + nb + vOff[i]);
            }
        }
        if (kv0 <= qw + 31) {                // warp has unmasked work
            // QK^T swapped: S^T[k][q], lane: q = c32, k = kv0 + 32*t2 + crow(r,hi)
            f32x16 s0 = {}, s1 = {};
            __builtin_amdgcn_s_setprio(1);
            #pragma unroll
            for (int dk = 0; dk < 4; ++dk) {
                s0 = mfma32(*(const bf16x8*)(fK + (0 * 4 + dk) * 512 + l * 8), aq[dk], s0);
                s1 = mfma32(*(const bf16x8*)(fK + (1 * 4 + dk) * 512 + l * 8), aq[dk], s1);
            }
            __builtin_amdgcn_s_setprio(0);
            if (kv0 + 63 > qw) {             // causal mask needed
                const int q = qw + c32;
                #pragma unroll
                for (int r = 0; r < 16; ++r) {
                    const int crow = (r & 3) + 8 * (r >> 2) + 4 * hi;
                    if (kv0 + crow > q)      s0[r] = -1e30f;
                    if (kv0 + 32 + crow > q) s1[r] = -1e30f;
                }
            }
            // p = exp2(s) in place; per-lane partial row sum (one q per lane)
            #pragma unroll
            for (int r = 0; r < 16; ++r) {
                s0[r] = exp2f(s0[r]);
                s1[r] = exp2f(s1[r]);
                lrow += s0[r] + s1[r];
            }
            // P -> PV A-fragments: per ks, 4 cvt_pk + 2 permlane32_swap
            __builtin_amdgcn_s_setprio(1);
            #define PV_STEP(PS, B8, KS)                                          \
            {                                                                    \
                u32 cA  = cvtpk(PS[B8 + 0], PS[B8 + 1]);                         \
                u32 cA2 = cvtpk(PS[B8 + 2], PS[B8 + 3]);                         \
                u32 cB  = cvtpk(PS[B8 + 4], PS[B8 + 5]);                         \
                u32 cB2 = cvtpk(PS[B8 + 6], PS[B8 + 7]);                         \
                PLSWAP(cA, cB); PLSWAP(cA2, cB2);                                \
                u32 w[4] = {cA, cA2, cB, cB2};                                   \
                bf16x8 pa = *(bf16x8*)w;                                         \
                o0 = mfma32(pa, *(const bf16x8*)(fV + (0 * 4 + (KS)) * 512 + l * 8), o0); \
                o1 = mfma32(pa, *(const bf16x8*)(fV + (1 * 4 + (KS)) * 512 + l * 8), o1); \
            }
            PV_STEP(s0, 0, 0)
            PV_STEP(s0, 8, 1)
            PV_STEP(s1, 0, 2)
            PV_STEP(s1, 8, 3)
            #undef PV_STEP
            __builtin_amdgcn_s_setprio(0);
        }
    }
    // row-sum: other k-half lives on lane l^32
    lrow += __shfl_xor(lrow, 32);
    lrL[wid * 32 + c32] = lrow;
    float invv[16];
    #pragma unroll
    for (int g = 0; g < 4; ++g) {
        float4 lv = *(const float4*)&lrL[wid * 32 + 8 * g + 4 * hi];
        invv[g * 4 + 0] = 1.0f / lv.x;
        invv[g * 4 + 1] = 1.0f / lv.y;
        invv[g * 4 + 2] = 1.0f / lv.z;
        invv[g * 4 + 3] = 1.0f / lv.w;
    }
    #pragma unroll
    for (int r = 0; r < 16; ++r) {
        const int q = qw + (r & 3) + 8 * (r >> 2) + 4 * hi;
        u16* zp = &Zb[(((size_t)b * SS + q) * HH + h) * DH_];
        zp[c32]      = f2bf(o0[r] * invv[r]);
        zp[32 + c32] = f2bf(o1[r] * invv[r]);
    }
}

// ---------------------------------------------------------------------------
// gemm_out: [4096,1024] @ [1024,1024] + b_O -> fp32
// ---------------------------------------------------------------------------
__global__ __launch_bounds__(256)
void gemm_out(const u16* __restrict__ Zb, const u16* __restrict__ WoT,
              const float* __restrict__ bO, float* __restrict__ out) {
    __shared__ __align__(16) u16 tA[128 * 64];
    __shared__ __align__(16) u16 tB[128 * 64];
    const int brow = blockIdx.x * 128, bcol = blockIdx.y * 128;
    const int t = threadIdx.x, wid = t >> 6, l = t & 63;
    const int wr = (wid >> 1) * 64, wc = (wid & 1) * 64;
    f32x4 acc[4][4] = {};
    for (int k0 = 0; k0 < DM_; k0 += 64) {
        __syncthreads();
        #pragma unroll
        for (int i = 0; i < 4; ++i) {
            const int off = i * 4096 + t * 16;
            const int row = off >> 7, colB = off & 127;
            gload16((const char*)Zb + ((size_t)(brow + row) * DM_ + k0) * 2 + colB,
                    (char*)tA + off);
            gload16((const char*)WoT + ((size_t)(bcol + row) * DM_ + k0) * 2 + colB,
                    (char*)tB + off);
        }
        __syncthreads();
        #pragma unroll
        for (int kc = 0; kc < 64; kc += 32) {
            bf16x8 a[4], b[4];
            #pragma unroll
            for (int i = 0; i < 4; ++i) a[i] = fragLd(tA, wr + i * 16, kc, 64);
            #pragma unroll
            for (int j = 0; j < 4; ++j) b[j] = fragLd(tB, wc + j * 16, kc, 64);
            #pragma unroll
            for (int i = 0; i < 4; ++i)
                #pragma unroll
                for (int j = 0; j < 4; ++j)
                    acc[i][j] = mfma16(a[i], b[j], acc[i][j]);
        }
    }
    #pragma unroll
    for (int i = 0; i < 4; ++i)
        #pragma unroll
        for (int j = 0; j < 4; ++j)
            #pragma unroll
            for (int r = 0; r < 4; ++r) {
                int row = brow + wr + i * 16 + ((l >> 4) << 2) + r;
                int col = bcol + wc + j * 16 + (l & 15);
                out[(size_t)row * DM_ + col] = acc[i][j][r] + bO[col];
            }
}

// ---------------------------------------------------------------------------
extern "C" void kernel_launch(void* const* d_in, const int* in_sizes, int n_in,
                              void* d_out, int out_size, void* d_ws, size_t ws_size,
                              hipStream_t stream) {
    const float* x  = (const float*)d_in[0];
    const float* wq = (const float*)d_in[1];
    const float* wk = (const float*)d_in[2];
    const float* wv = (const float*)d_in[3];
    const float* wo = (const float*)d_in[4];
    const float* bq = (const float*)d_in[5];
    const float* bk = (const float*)d_in[6];
    const float* bv = (const float*)d_in[7];
    const float* bO = (const float*)d_in[8];
    float* out = (float*)d_out;

    char* w = (char*)d_ws;
    u16* Xb  = (u16*)w;  w += (size_t)NROW * DM_ * 2;
    u16* Wt  = (u16*)w;  w += (size_t)NQKV * DM_ * 2;
    u16* WoT = (u16*)w;  w += (size_t)DM_ * DM_ * 2;
    float* biasQKV = (float*)w; w += (size_t)NQKV * 4;
    u16* Qs  = (u16*)w;  w += (size_t)BB * HH * SS * DH_ * 2;
    u16* Ks  = (u16*)w;  w += (size_t)BB * HH * SS * DH_ * 2;
    u16* Vt  = (u16*)w;  w += (size_t)BB * HH * SS * DH_ * 2;
    u16* Zb  = (u16*)w;  w += (size_t)BB * HH * SS * DH_ * 2;

    prep<<<1536, 256, 0, stream>>>(x, wq, wk, wv, wo, bq, bk, bv,
                                   Xb, Wt, WoT, biasQKV);
    gemm_qkv2<<<768, 256, 0, stream>>>(Xb, Wt, biasQKV, Qs, Ks, Vt);
    attn_fwd<<<512, 256, 0, stream>>>(Qs, Ks, Vt, Zb);
    gemm_out<<<dim3(NROW / 128, DM_ / 128), 256, 0, stream>>>(Zb, WoT, bO, out);
}

// Round 7
// 104.556 us; speedup vs baseline: 1.6733x; 1.2870x over previous
//
#include <hip/hip_runtime.h>
#include <hip/hip_bf16.h>

// Sizes for this problem instance
#define BB   2
#define SS   2048
#define HH   16
#define DM_  1024
#define DH_  64
#define NROW 4096   // BB*SS
#define NQKV 3072   // 3 * HH * DH

typedef unsigned short u16;
typedef unsigned int u32;
using short4v = __attribute__((ext_vector_type(4))) short;
using short8 = __attribute__((ext_vector_type(8))) short;
using bf16x8 = __attribute__((ext_vector_type(8))) __bf16;
using f32x4  = __attribute__((ext_vector_type(4))) float;
using f32x16 = __attribute__((ext_vector_type(16))) float;

// Q pre-scale: 1/sqrt(64) * 1/ln(2)  (so attention uses exp2 directly)
#define QSCALE 0.180336880f

__device__ __forceinline__ u16 f2bf(float f) {
    union { float f; unsigned u; } v; v.f = f;
    unsigned r = v.u + 0x7fffu + ((v.u >> 16) & 1u);
    return (u16)(r >> 16);
}

__device__ __forceinline__ f32x4 mfma16(bf16x8 a, bf16x8 b, f32x4 c) {
    return __builtin_amdgcn_mfma_f32_16x16x32_bf16(a, b, c, 0, 0, 0);
}
__device__ __forceinline__ f32x16 mfma32(bf16x8 a, bf16x8 b, f32x16 c) {
    return __builtin_amdgcn_mfma_f32_32x32x16_bf16(a, b, c, 0, 0, 0);
}

__device__ __forceinline__ u32 cvtpk(float lo, float hi) {
    u32 r;
    asm("v_cvt_pk_bf16_f32 %0, %1, %2" : "=v"(r) : "v"(lo), "v"(hi));
    return r;
}
#define PLSWAP(a, b) asm("v_permlane32_swap_b32 %0, %1" : "+v"(a), "+v"(b))

// async global->LDS, 16B per lane (dest = wave-uniform base + lane*16)
__device__ __forceinline__ void gload16(const void* g, void* l) {
    __builtin_amdgcn_global_load_lds(
        (const __attribute__((address_space(1))) void*)g,
        (__attribute__((address_space(3))) void*)l, 16, 0, 0);
}

// ---------------------------------------------------------------------------
// prep: fused pack_x (vectorized) + trans_w + trans_wo + bias pack
// ---------------------------------------------------------------------------
__global__ __launch_bounds__(256)
void prep(const float* __restrict__ x,  const float* __restrict__ wq,
          const float* __restrict__ wk, const float* __restrict__ wv,
          const float* __restrict__ wo, const float* __restrict__ bq,
          const float* __restrict__ bk, const float* __restrict__ bv,
          u16* __restrict__ Xb, u16* __restrict__ Wt,
          u16* __restrict__ WoT, float* __restrict__ biasQKV) {
    __shared__ float tile[64][65];
    const int bx = blockIdx.x, t = threadIdx.x;
    if (bx < 512) {
        const int tid = bx * 256 + t;
        #pragma unroll
        for (int it = 0; it < 8; ++it) {
            int i = tid + it * 131072;
            float4 v = ((const float4*)x)[i];
            u16 b4[4] = {f2bf(v.x), f2bf(v.y), f2bf(v.z), f2bf(v.w)};
            ((short4v*)Xb)[i] = *(short4v*)b4;
        }
        if (tid < NQKV) {
            int mat = tid >> 10, h = (tid >> 6) & 15, d = tid & 63;
            const float* bb = (mat == 0) ? bq : ((mat == 1) ? bk : bv);
            biasQKV[tid] = bb[h * DH_ + d];
        }
    } else if (bx < 1280) {
        const int idx = bx - 512;
        const int m0 = (idx & 15) * 64, hm = idx >> 4;
        const int mat = hm >> 4, h = hm & 15;
        const float* w = (mat == 0) ? wq : ((mat == 1) ? wk : wv);
        #pragma unroll
        for (int it = 0; it < 4; ++it) {
            int row = it * 16 + (t >> 4), c4 = (t & 15) * 4;
            float4 v = *(const float4*)&w[((size_t)h * 1024 + m0 + row) * 64 + c4];
            tile[row][c4] = v.x; tile[row][c4 + 1] = v.y;
            tile[row][c4 + 2] = v.z; tile[row][c4 + 3] = v.w;
        }
        __syncthreads();
        #pragma unroll
        for (int it = 0; it < 2; ++it) {
            int c = it * 256 + t, d = c >> 3, mc = (c & 7) * 8;
            u16 buf[8];
            #pragma unroll
            for (int j = 0; j < 8; ++j) buf[j] = f2bf(tile[mc + j][d]);
            *(short8*)&Wt[((size_t)(mat * 1024 + h * 64 + d)) * 1024 + m0 + mc] = *(short8*)buf;
        }
    } else {
        const int idx = bx - 1280;
        const int n0 = (idx & 15) * 64, k0 = (idx >> 4) * 64;
        #pragma unroll
        for (int it = 0; it < 4; ++it) {
            int row = it * 16 + (t >> 4), c4 = (t & 15) * 4;
            float4 v = *(const float4*)&wo[(size_t)(k0 + row) * DM_ + n0 + c4];
            tile[row][c4] = v.x; tile[row][c4 + 1] = v.y;
            tile[row][c4 + 2] = v.z; tile[row][c4 + 3] = v.w;
        }
        __syncthreads();
        #pragma unroll
        for (int it = 0; it < 2; ++it) {
            int c = it * 256 + t, n = c >> 3, kc = (c & 7) * 8;
            u16 buf[8];
            #pragma unroll
            for (int j = 0; j < 8; ++j) buf[j] = f2bf(tile[kc + j][n]);
            *(short8*)&WoT[(size_t)(n0 + n) * DM_ + k0 + kc] = *(short8*)buf;
        }
    }
}

// ---------------------------------------------------------------------------
// gemm_core_128: pipelined 128x128-tile GEMM body. 8 waves (2M x 4N), BK=64,
// double-buffered 64KB LDS, stage-next-first (loads fly under MFMA, drained
// by the single __syncthreads per K-step), T2 XOR-swizzle (pre-swizzled
// global source + swizzled ds_read_b128 -> conflict-free), setprio on MFMA.
// Per wave: 64x32 output = acc[4][2] f32x4.
// ---------------------------------------------------------------------------
__device__ __forceinline__ void gemm_core_128(
    const u16* __restrict__ Ap, const u16* __restrict__ Bp,
    int brow, int bcol, u16* lds, f32x4 acc[4][2]) {
    const int t = threadIdx.x, l = t & 63;
    const int wid = t >> 6, wm = wid >> 2, wn = wid & 3;
    // staging invariants: thread t owns chunks c0=t, c1=t+512 of each tile
    const int c0 = t, c1 = t + 512;
    const int r0 = c0 >> 3, sb0 = ((c0 & 7) ^ (r0 & 7)) << 3;  // swizzled src col
    const int r1 = c1 >> 3, sb1 = ((c1 & 7) ^ (r1 & 7)) << 3;
    u16* A0 = lds;            // [2][128][64] u16
    u16* B0 = lds + 16384;
    const int rA0 = wm * 64 + (l & 15);      // frag row bases
    const int rB0 = wn * 32 + (l & 15);
    const int sw  = (l & 7) << 3;            // read swizzle (row&7 == l&7 here)
    const int colA = ((l >> 4) << 3);        // k-subcol from lane

    // prologue: stage tile 0 into buf 0
    {
        gload16(Ap + (size_t)(brow + r0) * DM_ + sb0, A0 + c0 * 8);
        gload16(Ap + (size_t)(brow + r1) * DM_ + sb1, A0 + c1 * 8);
        gload16(Bp + (size_t)(bcol + r0) * DM_ + sb0, B0 + c0 * 8);
        gload16(Bp + (size_t)(bcol + r1) * DM_ + sb1, B0 + c1 * 8);
    }
    __syncthreads();
    for (int kt = 0; kt < 16; ++kt) {
        const int p = kt & 1;
        if (kt < 15) {   // stage next tile into other buffer (drained by sync below)
            const int ko = (kt + 1) * 64;
            gload16(Ap + (size_t)(brow + r0) * DM_ + ko + sb0, A0 + (p ^ 1) * 8192 + c0 * 8);
            gload16(Ap + (size_t)(brow + r1) * DM_ + ko + sb1, A0 + (p ^ 1) * 8192 + c1 * 8);
            gload16(Bp + (size_t)(bcol + r0) * DM_ + ko + sb0, B0 + (p ^ 1) * 8192 + c0 * 8);
            gload16(Bp + (size_t)(bcol + r1) * DM_ + ko + sb1, B0 + (p ^ 1) * 8192 + c1 * 8);
        }
        const u16* Ab = A0 + p * 8192;
        const u16* Bb = B0 + p * 8192;
        #pragma unroll
        for (int kc = 0; kc < 64; kc += 32) {
            const int cx = (kc + colA) ^ sw;
            bf16x8 af[4], bfr[2];
            #pragma unroll
            for (int m = 0; m < 4; ++m)
                af[m] = *(const bf16x8*)(Ab + (rA0 + m * 16) * 64 + cx);
            #pragma unroll
            for (int n = 0; n < 2; ++n)
                bfr[n] = *(const bf16x8*)(Bb + (rB0 + n * 16) * 64 + cx);
            __builtin_amdgcn_s_setprio(1);
            #pragma unroll
            for (int m = 0; m < 4; ++m)
                #pragma unroll
                for (int n = 0; n < 2; ++n)
                    acc[m][n] = mfma16(af[m], bfr[n], acc[m][n]);
            __builtin_amdgcn_s_setprio(0);
        }
        __syncthreads();   // drains this iter's stage loads + releases buf p
    }
}

// ---------------------------------------------------------------------------
// gemm_qkv3: blocks 0..511: [4096,1024]@[1024,2048] -> Q(scaled), K
//            blocks 512..767: Vt = WtV @ Xb^T -> Vt[b*1024+n'][s]
// LDS-transposed bf16 epilogue: coalesced 64B store chunks.
// ---------------------------------------------------------------------------
__global__ __launch_bounds__(512)
void gemm_qkv3(const u16* __restrict__ Xb, const u16* __restrict__ Wt,
               const float* __restrict__ bias, u16* __restrict__ Qs,
               u16* __restrict__ Ks, u16* __restrict__ Vt) {
    __shared__ __align__(16) u16 lds[32768];   // 64 KB
    const int bx = blockIdx.x, t = threadIdx.x, l = t & 63;
    const int wid = t >> 6, wm = wid >> 2, wn = wid & 3;
    f32x4 acc[4][2] = {};
    const bool isV = (bx >= 512);
    int brow, bcol; const u16 *Ap, *Bp;
    if (!isV) { brow = (bx & 31) * 128; bcol = (bx >> 5) * 128; Ap = Xb; Bp = Wt; }
    else { int i2 = bx - 512; brow = (i2 & 7) * 128; bcol = (i2 >> 3) * 128;
           Ap = Wt + (size_t)2048 * DM_; Bp = Xb; }
    gemm_core_128(Ap, Bp, brow, bcol, lds, acc);

    // ---- epilogue: wave region [64 rows][32 cols] u16 at wid*2048
    u16* wr_ = lds + wid * 2048;
    const int colbase = bcol + wn * 32;
    const int rowbase = brow + wm * 64;
    const int rsub = ((l >> 4) << 2);
    if (!isV) {
        const float b0 = bias[colbase + (l & 15)];
        const float b1 = bias[colbase + 16 + (l & 15)];
        const float scl = (colbase < 1024) ? QSCALE : 1.0f;
        #pragma unroll
        for (int m = 0; m < 4; ++m)
            #pragma unroll
            for (int n = 0; n < 2; ++n) {
                const float bb = n ? b1 : b0;
                #pragma unroll
                for (int r = 0; r < 4; ++r)
                    wr_[(m * 16 + rsub + r) * 32 + n * 16 + (l & 15)] =
                        f2bf((acc[m][n][r] + bb) * scl);
            }
    } else {
        #pragma unroll
        for (int m = 0; m < 4; ++m) {
            float4 bv = *(const float4*)&bias[2048 + rowbase + m * 16 + rsub];
            const float bbr[4] = {bv.x, bv.y, bv.z, bv.w};
            #pragma unroll
            for (int n = 0; n < 2; ++n)
                #pragma unroll
                for (int r = 0; r < 4; ++r)
                    wr_[(m * 16 + rsub + r) * 32 + n * 16 + (l & 15)] =
                        f2bf(acc[m][n][r] + bbr[r]);
        }
    }
    __syncthreads();
    if (!isV) {
        const int hsel = (colbase >> 6) & 15, d0 = colbase & 63;
        const int bsel = rowbase >> 11, s0 = rowbase & 2047;
        u16* outp = (colbase < 1024) ? Qs : Ks;
        #pragma unroll
        for (int p = 0; p < 4; ++p) {
            const int rr = p * 16 + (l >> 2);
            short8 v = *(const short8*)(wr_ + rr * 32 + (l & 3) * 8);
            *(short8*)&outp[(((size_t)bsel * HH + hsel) * SS + s0 + rr) * DH_ + d0 + (l & 3) * 8] = v;
        }
    } else {
        const int bsel = colbase >> 11, s0 = colbase & 2047;
        #pragma unroll
        for (int p = 0; p < 4; ++p) {
            const int rr = p * 16 + (l >> 2);
            short8 v = *(const short8*)(wr_ + rr * 32 + (l & 3) * 8);
            *(short8*)&Vt[((size_t)bsel * 1024 + rowbase + rr) * SS + s0 + (l & 3) * 8] = v;
        }
    }
}

// ---------------------------------------------------------------------------
// gemm_out3: [4096,1024] @ [1024,1024] + b_O -> fp32, same pipelined core
// ---------------------------------------------------------------------------
__global__ __launch_bounds__(512)
void gemm_out3(const u16* __restrict__ Zb, const u16* __restrict__ WoT,
               const float* __restrict__ bO, float* __restrict__ out) {
    __shared__ __align__(16) u16 lds[32768];
    const int bx = blockIdx.x, t = threadIdx.x, l = t & 63;
    const int wid = t >> 6, wm = wid >> 2, wn = wid & 3;
    const int brow = (bx & 31) * 128, bcol = (bx >> 5) * 128;
    f32x4 acc[4][2] = {};
    gemm_core_128(Zb, WoT, brow, bcol, lds, acc);
    const int colbase = bcol + wn * 32;
    const int rowbase = brow + wm * 64;
    const int rsub = ((l >> 4) << 2);
    const float b0 = bO[colbase + (l & 15)];
    const float b1 = bO[colbase + 16 + (l & 15)];
    #pragma unroll
    for (int m = 0; m < 4; ++m)
        #pragma unroll
        for (int n = 0; n < 2; ++n) {
            const float bb = n ? b1 : b0;
            #pragma unroll
            for (int r = 0; r < 4; ++r)
                out[(size_t)(rowbase + m * 16 + rsub + r) * DM_ + colbase + n * 16 + (l & 15)] =
                    acc[m][n][r] + bb;
        }
}

// ---------------------------------------------------------------------------
// attn: swapped-QK 32x32 MFMA flash attention (unchanged from round 6)
// ---------------------------------------------------------------------------
__global__ __launch_bounds__(256)
void attn_fwd(const u16* __restrict__ Qs, const u16* __restrict__ Ks,
              const u16* __restrict__ Vt, u16* __restrict__ Zb) {
    __shared__ __align__(16) u16 fK[4096];   // 64 kseq x 64 d, fragment-linear
    __shared__ __align__(16) u16 fV[4096];   // 64 d x 64 kseq, fragment-linear
    __shared__ float lrL[128];
    const int bidx = blockIdx.x;
    const int qt = 15 - (bidx >> 5);
    const int bh = bidx & 31, b = bh >> 4, h = bh & 15;
    const int t = threadIdx.x, wid = t >> 6, l = t & 63;
    const int hi = l >> 5, c32 = l & 31;
    const u16* Qp = Qs + (size_t)bh * SS * DH_;
    const u16* Kp = Ks + (size_t)bh * SS * DH_;
    const u16* Vp = Vt + (size_t)bh * DH_ * SS;
    const int q0 = qt * 128;
    const int qw = q0 + wid * 32;
    const int nt = 2 * qt + 2;

    bf16x8 aq[4];
    #pragma unroll
    for (int dk = 0; dk < 4; ++dk)
        aq[dk] = *(const bf16x8*)&Qp[(size_t)(qw + c32) * DH_ + dk * 16 + hi * 8];

    int kOff[2]; size_t vOff[2]; u16 *dK[2], *dV[2];
    #pragma unroll
    for (int i = 0; i < 2; ++i) {
        const int c = t + 256 * i, sec = c >> 6, ln = c & 63;
        kOff[i] = ((sec >> 2) * 32 + (ln & 31)) * DH_ + (sec & 3) * 16 + (ln >> 5) * 8;
        vOff[i] = (size_t)((sec >> 2) * 32 + (ln & 31)) * SS + (sec & 3) * 16 + (ln >> 5) * 8;
        dK[i] = fK + c * 8;
        dV[i] = fV + c * 8;
    }

    short8 kA[2], vA[2];
    #pragma unroll
    for (int i = 0; i < 2; ++i) {
        kA[i] = *(const short8*)(Kp + kOff[i]);
        vA[i] = *(const short8*)(Vp + vOff[i]);
    }

    f32x16 o0 = {}, o1 = {};
    float lrow = 0.f;

    for (int kt = 0; kt < nt; ++kt) {
        const int kv0 = kt * 64;
        __syncthreads();
        *(short8*)dK[0] = kA[0]; *(short8*)dK[1] = kA[1];
        *(short8*)dV[0] = vA[0]; *(short8*)dV[1] = vA[1];
        __syncthreads();
        if (kt + 1 < nt) {
            const int nb = (kt + 1) * 64;
            #pragma unroll
            for (int i = 0; i < 2; ++i) {
                kA[i] = *(const short8*)(Kp + (size_t)nb * DH_ + kOff[i]);
                vA[i] = *(const short8*)(Vp + nb + vOff[i]);
            }
        }
        if (kv0 <= qw + 31) {
            f32x16 s0 = {}, s1 = {};
            __builtin_amdgcn_s_setprio(1);
            #pragma unroll
            for (int dk = 0; dk < 4; ++dk) {
                s0 = mfma32(*(const bf16x8*)(fK + (0 * 4 + dk) * 512 + l * 8), aq[dk], s0);
                s1 = mfma32(*(const bf16x8*)(fK + (1 * 4 + dk) * 512 + l * 8), aq[dk], s1);
            }
            __builtin_amdgcn_s_setprio(0);
            if (kv0 + 63 > qw) {
                const int q = qw + c32;
                #pragma unroll
                for (int r = 0; r < 16; ++r) {
                    const int crow = (r & 3) + 8 * (r >> 2) + 4 * hi;
                    if (kv0 + crow > q)      s0[r] = -1e30f;
                    if (kv0 + 32 + crow > q) s1[r] = -1e30f;
                }
            }
            #pragma unroll
            for (int r = 0; r < 16; ++r) {
                s0[r] = exp2f(s0[r]);
                s1[r] = exp2f(s1[r]);
                lrow += s0[r] + s1[r];
            }
            __builtin_amdgcn_s_setprio(1);
            #define PV_STEP(PS, B8, KS)                                          \
            {                                                                    \
                u32 cA  = cvtpk(PS[B8 + 0], PS[B8 + 1]);                         \
                u32 cA2 = cvtpk(PS[B8 + 2], PS[B8 + 3]);                         \
                u32 cB  = cvtpk(PS[B8 + 4], PS[B8 + 5]);                         \
                u32 cB2 = cvtpk(PS[B8 + 6], PS[B8 + 7]);                         \
                PLSWAP(cA, cB); PLSWAP(cA2, cB2);                                \
                u32 w[4] = {cA, cA2, cB, cB2};                                   \
                bf16x8 pa = *(bf16x8*)w;                                         \
                o0 = mfma32(pa, *(const bf16x8*)(fV + (0 * 4 + (KS)) * 512 + l * 8), o0); \
                o1 = mfma32(pa, *(const bf16x8*)(fV + (1 * 4 + (KS)) * 512 + l * 8), o1); \
            }
            PV_STEP(s0, 0, 0)
            PV_STEP(s0, 8, 1)
            PV_STEP(s1, 0, 2)
            PV_STEP(s1, 8, 3)
            #undef PV_STEP
            __builtin_amdgcn_s_setprio(0);
        }
    }
    lrow += __shfl_xor(lrow, 32);
    lrL[wid * 32 + c32] = lrow;
    float invv[16];
    #pragma unroll
    for (int g = 0; g < 4; ++g) {
        float4 lv = *(const float4*)&lrL[wid * 32 + 8 * g + 4 * hi];
        invv[g * 4 + 0] = 1.0f / lv.x;
        invv[g * 4 + 1] = 1.0f / lv.y;
        invv[g * 4 + 2] = 1.0f / lv.z;
        invv[g * 4 + 3] = 1.0f / lv.w;
    }
    #pragma unroll
    for (int r = 0; r < 16; ++r) {
        const int q = qw + (r & 3) + 8 * (r >> 2) + 4 * hi;
        u16* zp = &Zb[(((size_t)b * SS + q) * HH + h) * DH_];
        zp[c32]      = f2bf(o0[r] * invv[r]);
        zp[32 + c32] = f2bf(o1[r] * invv[r]);
    }
}

// ---------------------------------------------------------------------------
extern "C" void kernel_launch(void* const* d_in, const int* in_sizes, int n_in,
                              void* d_out, int out_size, void* d_ws, size_t ws_size,
                              hipStream_t stream) {
    const float* x  = (const float*)d_in[0];
    const float* wq = (const float*)d_in[1];
    const float* wk = (const float*)d_in[2];
    const float* wv = (const float*)d_in[3];
    const float* wo = (const float*)d_in[4];
    const float* bq = (const float*)d_in[5];
    const float* bk = (const float*)d_in[6];
    const float* bv = (const float*)d_in[7];
    const float* bO = (const float*)d_in[8];
    float* out = (float*)d_out;

    char* w = (char*)d_ws;
    u16* Xb  = (u16*)w;  w += (size_t)NROW * DM_ * 2;
    u16* Wt  = (u16*)w;  w += (size_t)NQKV * DM_ * 2;
    u16* WoT = (u16*)w;  w += (size_t)DM_ * DM_ * 2;
    float* biasQKV = (float*)w; w += (size_t)NQKV * 4;
    u16* Qs  = (u16*)w;  w += (size_t)BB * HH * SS * DH_ * 2;
    u16* Ks  = (u16*)w;  w += (size_t)BB * HH * SS * DH_ * 2;
    u16* Vt  = (u16*)w;  w += (size_t)BB * HH * SS * DH_ * 2;
    u16* Zb  = (u16*)w;  w += (size_t)BB * HH * SS * DH_ * 2;

    prep<<<1536, 256, 0, stream>>>(x, wq, wk, wv, wo, bq, bk, bv,
                                   Xb, Wt, WoT, biasQKV);
    gemm_qkv3<<<768, 512, 0, stream>>>(Xb, Wt, biasQKV, Qs, Ks, Vt);
    attn_fwd<<<512, 256, 0, stream>>>(Qs, Ks, Vt, Zb);
    gemm_out3<<<256, 512, 0, stream>>>(Zb, WoT, bO, out);
}